// Round 5
// baseline (63.345 us; speedup 1.0000x reference)
//
#include <hip/hip_runtime.h>
#include <hip/hip_fp16.h>
#include <cstdint>
#include <cstddef>

#define B_ 8
#define N_ 256
#define D_ 128
#define H_ 128
#define K_ 8

typedef _Float16 f16x8 __attribute__((ext_vector_type(8)));
typedef _Float16 f16x2 __attribute__((ext_vector_type(2)));
typedef float    f32x4 __attribute__((ext_vector_type(4)));

static __device__ __forceinline__ unsigned packh2(float lo, float hi) {
    unsigned a = __half_as_ushort(__float2half(lo));
    unsigned b = __half_as_ushort(__float2half(hi));
    return a | (b << 16);
}

// ---------------------------------------------------------------------------
// prep_all: one kernel, three jobs selected by blockIdx.x
//   [0,256)   : Eh = fp16(E)
//   [256,320) : Wh[k][c][d] = fp16( W1[k][(c<128? d : 128+d)][c&127] )
//   320       : wdh (half2 of W2 col-diff) + consts
// ---------------------------------------------------------------------------
__global__ __launch_bounds__(256) void prep_all(
        const float* __restrict__ E, const float* __restrict__ W1,
        const float* __restrict__ W2, const float* __restrict__ b2,
        const float* __restrict__ W3, const float* __restrict__ b3,
        __half* __restrict__ Eh, __half* __restrict__ Wh,
        unsigned* __restrict__ wdh, float* __restrict__ consts) {
    __shared__ float Ws[128][33];
    const int bid = blockIdx.x;
    const int t   = threadIdx.x;

    if (bid < 256) {
        int idx = (bid * 256 + t) * 4;
        float4 v = *(const float4*)&E[idx];
        uint2 o;
        o.x = packh2(v.x, v.y);
        o.y = packh2(v.z, v.w);
        *(uint2*)&Eh[idx] = o;
    } else if (bid < 320) {
        const int kb = bid - 256;
        const int ct = kb & 7;
        const int k  = kb >> 3;
        const int c0 = ct * 32;
        const int ro = (c0 < 128) ? 0 : 128;
        const int h0 = c0 & 127;
        #pragma unroll
        for (int rep = 0; rep < 16; rep++) {
            int idx = rep * 256 + t;
            int d   = idx >> 5;
            int cl  = idx & 31;
            Ws[d][cl] = W1[((size_t)(k * 256 + ro + d)) * H_ + h0 + cl];
        }
        __syncthreads();
        const int cl = t >> 3;   // 0..31
        const int dg = t & 7;    // 0..7 (16 d each)
        __half tmp[16];
        #pragma unroll
        for (int e = 0; e < 16; e++) tmp[e] = __float2half(Ws[dg * 16 + e][cl]);
        *(float4*)&Wh[((size_t)(k * 256 + c0 + cl)) * D_ + dg * 16]     = *(float4*)&tmp[0];
        *(float4*)&Wh[((size_t)(k * 256 + c0 + cl)) * D_ + dg * 16 + 8] = *(float4*)&tmp[8];
    } else {
        for (int idx = t; idx < K_ * 64; idx += 256) {  // idx = k*64 + hh
            int base = idx * 2;
            float w0 = W2[base * 2]     - W2[base * 2 + 1];
            float w1 = W2[base * 2 + 2] - W2[base * 2 + 3];
            wdh[idx] = packh2(w0, w1);
        }
        if (t < K_) {
            consts[t * 4 + 0] = b2[t * 2] - b2[t * 2 + 1];
            consts[t * 4 + 1] = W3[t * 2] - W3[t * 2 + 1];
            consts[t * 4 + 2] = W3[t * 2 + 1] + b3[t];
        }
    }
}

// ---------------------------------------------------------------------------
// fused: per block (bk, 64x64 i/j tile):
//   stage A (MFMA): waves 0,1 -> his[64][128] = Eh[i-tile] @ Wh[:,0:128] + b1
//                   waves 2,3 -> hjs[64][128] = Eh[j-tile] @ Wh[:,128:256]
//   stage B (VALU): asm v_pk_add_f16 + v_pk_max_f16 + 2x v_fma_mix_f32
// ---------------------------------------------------------------------------
__global__ __launch_bounds__(256, 4) void fused_kernel(
        const __half* __restrict__ Eh, const __half* __restrict__ Wh,
        const float* __restrict__ b1, const unsigned* __restrict__ wdh,
        const float* __restrict__ consts, float* __restrict__ out) {
    __shared__ __half his[64 * 136];
    __shared__ __half hjs[64 * 136];
    __shared__ unsigned wlds[64];

    const int bid = blockIdx.x;
    const int jt  = bid & 3;
    const int it  = (bid >> 2) & 3;
    const int bk  = bid >> 4;
    const int k   = bk & (K_ - 1);
    const int b   = bk >> 3;
    const int i0  = it * 64, j0 = jt * 64;
    const int t   = threadIdx.x;
    const int wv   = t >> 6;
    const int lane = t & 63;
    const int lr   = lane & 15, lk = lane >> 4;

    if (t < 64) wlds[t] = wdh[k * 64 + t];

    // ---- stage A: produce his / hjs via MFMA ----
    {
        const bool isJ   = (wv >= 2);
        const int  half32 = wv & 1;
        const int  rowbase = (isJ ? j0 : i0) + half32 * 32;
        const int  cbase   = isJ ? 128 : 0;
        __half* __restrict__ dst = isJ ? hjs : his;

        f16x8 A[2][4];
        #pragma unroll
        for (int mi = 0; mi < 2; mi++)
            #pragma unroll
            for (int kk = 0; kk < 4; kk++)
                A[mi][kk] = *(const f16x8*)&Eh[
                    ((size_t)(b * N_ + rowbase + mi * 16 + lr)) * D_ + kk * 32 + lk * 8];

        #pragma unroll
        for (int nc = 0; nc < 8; nc++) {
            f16x8 Bf[4];
            #pragma unroll
            for (int kk = 0; kk < 4; kk++)
                Bf[kk] = *(const f16x8*)&Wh[
                    ((size_t)(k * 256 + cbase + nc * 16 + lr)) * D_ + kk * 32 + lk * 8];
            const int hcol = nc * 16 + lr;
            const float bias = isJ ? 0.f : b1[k * H_ + hcol];
            #pragma unroll
            for (int mi = 0; mi < 2; mi++) {
                f32x4 acc = {0.f, 0.f, 0.f, 0.f};
                #pragma unroll
                for (int kk = 0; kk < 4; kk++)
                    acc = __builtin_amdgcn_mfma_f32_16x16x32_f16(A[mi][kk], Bf[kk], acc, 0, 0, 0);
                const int lrow = half32 * 32 + mi * 16 + lk * 4;
                #pragma unroll
                for (int q = 0; q < 4; q++)
                    dst[(lrow + q) * 136 + hcol] = __float2half(acc[q] + bias);
            }
        }
    }
    __syncthreads();

    // ---- stage B: pairwise packed-f16 relu-dot, deterministic ISel via asm ----
    const float b2d = consts[k * 4 + 0];
    const float w3d = consts[k * 4 + 1];
    const float w3b = consts[k * 4 + 2];
    const int tx = t & 15;   // j = j0 + tx + 16c
    const int ty = t >> 4;   // i = i0 + ty + 16a

    float accL[4][4], accH[4][4];
    #pragma unroll
    for (int a = 0; a < 4; a++)
        #pragma unroll
        for (int c = 0; c < 4; c++) { accL[a][c] = b2d; accH[a][c] = 0.f; }

    #pragma unroll 2
    for (int hq = 0; hq < 16; hq++) {   // 8 h per iter
        unsigned Wv[4];
        *(uint4*)&Wv[0] = *(const uint4*)&wlds[hq * 4];
        unsigned Aa[4][4], Bb[4][4];
        #pragma unroll
        for (int a = 0; a < 4; a++)
            *(uint4*)&Aa[a][0] = *(const uint4*)&his[(ty + 16 * a) * 136 + hq * 8];
        #pragma unroll
        for (int c = 0; c < 4; c++)
            *(uint4*)&Bb[c][0] = *(const uint4*)&hjs[(tx + 16 * c) * 136 + hq * 8];

        #pragma unroll
        for (int e = 0; e < 4; e++) {
            #pragma unroll
            for (int a = 0; a < 4; a++) {
                #pragma unroll
                for (int c = 0; c < 4; c++) {
                    unsigned pre, act;
                    asm("v_pk_add_f16 %0, %1, %2" : "=v"(pre)
                        : "v"(Aa[a][e]), "v"(Bb[c][e]));
                    asm("v_pk_max_f16 %0, %1, 0" : "=v"(act) : "v"(pre));
                    asm("v_fma_mix_f32 %0, %1, %2, %0 op_sel:[0,0,0] op_sel_hi:[1,1,0]"
                        : "+v"(accL[a][c]) : "v"(act), "v"(Wv[e]));
                    asm("v_fma_mix_f32 %0, %1, %2, %0 op_sel:[1,1,0] op_sel_hi:[1,1,0]"
                        : "+v"(accH[a][c]) : "v"(act), "v"(Wv[e]));
                }
            }
        }
    }

    #pragma unroll
    for (int a = 0; a < 4; a++) {
        int i = i0 + ty + 16 * a;
        #pragma unroll
        for (int c = 0; c < 4; c++) {
            float av = accL[a][c] + accH[a][c];
            float tt = av * 0.25f;
            float dd = fabsf(tt);
            float ss = sqrtf(fmaxf(0.5f - dd * dd, 0.f));
            float p0i = (ss + tt) * (ss + tt);
            float p0 = (dd >= 0.5f) ? (tt > 0.f ? 1.f : 0.f) : p0i;
            float val = fmaf(p0, w3d, w3b);
            int j = j0 + tx + 16 * c;
            if (i == j) val = 0.f;
            out[((size_t)bk * N_ + i) * N_ + j] = val;
        }
    }
}

// ---------------------------------------------------------------------------
extern "C" void kernel_launch(void* const* d_in, const int* in_sizes, int n_in,
                              void* d_out, int out_size, void* d_ws, size_t ws_size,
                              hipStream_t stream) {
    (void)in_sizes; (void)n_in; (void)out_size; (void)ws_size;
    const float* E  = (const float*)d_in[0];
    const float* W1 = (const float*)d_in[1];
    const float* b1 = (const float*)d_in[2];
    const float* W2 = (const float*)d_in[3];
    const float* b2 = (const float*)d_in[4];
    const float* W3 = (const float*)d_in[5];
    const float* b3 = (const float*)d_in[6];
    float* out = (float*)d_out;

    char* ws = (char*)d_ws;
    unsigned* wdh    = (unsigned*)ws;                    // K*64 half2 = 2 KB
    float*    consts = (float*)(ws + 4096);              // K*4 floats
    __half*   Eh     = (__half*)(ws + 8192);             // 512 KB
    __half*   Wh     = (__half*)(ws + 8192 + 524288);    // 512 KB

    prep_all<<<321, 256, 0, stream>>>(E, W1, W2, b2, W3, b3, Eh, Wh, wdh, consts);
    fused_kernel<<<B_ * K_ * 16, 256, 0, stream>>>(Eh, Wh, b1, wdh, consts, out);
}

// Round 6
// 58.778 us; speedup vs baseline: 1.0777x; 1.0777x over previous
//
#include <hip/hip_runtime.h>
#include <hip/hip_fp16.h>
#include <cstdint>
#include <cstddef>

#define B_ 8
#define N_ 256
#define D_ 128
#define H_ 128
#define K_ 8

typedef _Float16 f16x8 __attribute__((ext_vector_type(8)));
typedef _Float16 f16x2 __attribute__((ext_vector_type(2)));
typedef float    f32x4 __attribute__((ext_vector_type(4)));

static __device__ __forceinline__ f16x2 h2cast(unsigned u) {
    return __builtin_bit_cast(f16x2, u);
}
static __device__ __forceinline__ unsigned packh2(float lo, float hi) {
    unsigned a = __half_as_ushort(__float2half(lo));
    unsigned b = __half_as_ushort(__float2half(hi));
    return a | (b << 16);
}

// ---------------------------------------------------------------------------
// prep_all: one kernel, three jobs selected by blockIdx.x
//   [0,256)   : Eh = fp16(E)
//   [256,320) : Wh[k][c][d] = fp16( W1[k][(c<128? d : 128+d)][c&127] )
//   320       : wdh (half2 of W2 col-diff) + consts
// ---------------------------------------------------------------------------
__global__ __launch_bounds__(256) void prep_all(
        const float* __restrict__ E, const float* __restrict__ W1,
        const float* __restrict__ W2, const float* __restrict__ b2,
        const float* __restrict__ W3, const float* __restrict__ b3,
        __half* __restrict__ Eh, __half* __restrict__ Wh,
        unsigned* __restrict__ wdh, float* __restrict__ consts) {
    __shared__ float Ws[128][33];
    const int bid = blockIdx.x;
    const int t   = threadIdx.x;

    if (bid < 256) {
        int idx = (bid * 256 + t) * 4;
        float4 v = *(const float4*)&E[idx];
        uint2 o;
        o.x = packh2(v.x, v.y);
        o.y = packh2(v.z, v.w);
        *(uint2*)&Eh[idx] = o;
    } else if (bid < 320) {
        const int kb = bid - 256;
        const int ct = kb & 7;
        const int k  = kb >> 3;
        const int c0 = ct * 32;
        const int ro = (c0 < 128) ? 0 : 128;
        const int h0 = c0 & 127;
        #pragma unroll
        for (int rep = 0; rep < 16; rep++) {
            int idx = rep * 256 + t;
            int d   = idx >> 5;
            int cl  = idx & 31;
            Ws[d][cl] = W1[((size_t)(k * 256 + ro + d)) * H_ + h0 + cl];
        }
        __syncthreads();
        const int cl = t >> 3;   // 0..31
        const int dg = t & 7;    // 0..7 (16 d each)
        __half tmp[16];
        #pragma unroll
        for (int e = 0; e < 16; e++) tmp[e] = __float2half(Ws[dg * 16 + e][cl]);
        *(float4*)&Wh[((size_t)(k * 256 + c0 + cl)) * D_ + dg * 16]     = *(float4*)&tmp[0];
        *(float4*)&Wh[((size_t)(k * 256 + c0 + cl)) * D_ + dg * 16 + 8] = *(float4*)&tmp[8];
    } else {
        for (int idx = t; idx < K_ * 64; idx += 256) {  // idx = k*64 + hh
            int base = idx * 2;
            float w0 = W2[base * 2]     - W2[base * 2 + 1];
            float w1 = W2[base * 2 + 2] - W2[base * 2 + 3];
            wdh[idx] = packh2(w0, w1);
        }
        if (t < K_) {
            consts[t * 4 + 0] = b2[t * 2] - b2[t * 2 + 1];
            consts[t * 4 + 1] = W3[t * 2] - W3[t * 2 + 1];
            consts[t * 4 + 2] = W3[t * 2 + 1] + b3[t];
        }
    }
}

// ---------------------------------------------------------------------------
// fused v2: block = (bk, 128i x 64j tile).
//   stage A (MFMA): 192 rows (hi 0..127 -> his, hj 0..63 -> hjs), 48 rows/wave
//   stage B (VALU): 8x4 micro-tile/thread, packed f16 relu-dot via fdot2
// ---------------------------------------------------------------------------
__global__ __launch_bounds__(256, 2) void fused_kernel(
        const __half* __restrict__ Eh, const __half* __restrict__ Wh,
        const float* __restrict__ b1, const unsigned* __restrict__ wdh,
        const float* __restrict__ consts, float* __restrict__ out) {
    __shared__ __half his[128 * 136];
    __shared__ __half hjs[64 * 136];
    __shared__ unsigned wlds[64];

    const int bid = blockIdx.x;
    const int jt  = bid & 3;            // 4 j-tiles of 64
    const int it  = (bid >> 2) & 1;     // 2 i-tiles of 128
    const int bk  = bid >> 3;
    const int k   = bk & (K_ - 1);
    const int b   = bk >> 3;
    const int i0  = it * 128, j0 = jt * 64;
    const int t   = threadIdx.x;
    const int wv   = t >> 6;
    const int lane = t & 63;
    const int lr   = lane & 15, lk = lane >> 4;

    if (t < 64) wlds[t] = wdh[k * 64 + t];

    // ---- stage A: produce his(128 rows) / hjs(64 rows) via MFMA ----
    #pragma unroll
    for (int rb = 0; rb < 3; rb++) {
        const int row16 = wv * 48 + rb * 16;            // 0..176, 16-aligned
        const bool isJ  = (row16 >= 128);
        const int rowg  = isJ ? (j0 + row16 - 128) : (i0 + row16);
        const int cbase = isJ ? 128 : 0;
        __half* __restrict__ dst = isJ ? &hjs[(row16 - 128) * 136] : &his[row16 * 136];

        f16x8 A[4];
        #pragma unroll
        for (int kk = 0; kk < 4; kk++)
            A[kk] = *(const f16x8*)&Eh[
                ((size_t)(b * N_ + rowg + lr)) * D_ + kk * 32 + lk * 8];

        #pragma unroll
        for (int nc = 0; nc < 8; nc++) {
            f16x8 Bf[4];
            #pragma unroll
            for (int kk = 0; kk < 4; kk++)
                Bf[kk] = *(const f16x8*)&Wh[
                    ((size_t)(k * 256 + cbase + nc * 16 + lr)) * D_ + kk * 32 + lk * 8];
            const int hcol = nc * 16 + lr;
            const float bias = isJ ? 0.f : b1[k * H_ + hcol];
            f32x4 acc = {0.f, 0.f, 0.f, 0.f};
            #pragma unroll
            for (int kk = 0; kk < 4; kk++)
                acc = __builtin_amdgcn_mfma_f32_16x16x32_f16(A[kk], Bf[kk], acc, 0, 0, 0);
            #pragma unroll
            for (int q = 0; q < 4; q++)
                dst[(lk * 4 + q) * 136 + hcol] = __float2half(acc[q] + bias);
        }
    }
    __syncthreads();

    // ---- stage B: pairwise packed-f16 relu-dot, 8x4 outputs/thread ----
    const float b2d = consts[k * 4 + 0];
    const float w3d = consts[k * 4 + 1];
    const float w3b = consts[k * 4 + 2];
    const int tx = t & 15;   // j = j0 + tx + 16c, c in 0..3
    const int ty = t >> 4;   // i = i0 + ty + 16a, a in 0..7

    float acc[8][4];
    #pragma unroll
    for (int a = 0; a < 8; a++)
        #pragma unroll
        for (int c = 0; c < 4; c++) acc[a][c] = b2d;

    const f16x2 zz = {(_Float16)0, (_Float16)0};

    #pragma unroll 2
    for (int hq = 0; hq < 16; hq++) {   // 8 h per iter
        unsigned Wv[4];
        *(uint4*)&Wv[0] = *(const uint4*)&wlds[hq * 4];
        unsigned Aa[8][4], Bb[4][4];
        #pragma unroll
        for (int a = 0; a < 8; a++)
            *(uint4*)&Aa[a][0] = *(const uint4*)&his[(ty + 16 * a) * 136 + hq * 8];
        #pragma unroll
        for (int c = 0; c < 4; c++)
            *(uint4*)&Bb[c][0] = *(const uint4*)&hjs[(tx + 16 * c) * 136 + hq * 8];

        #pragma unroll
        for (int e = 0; e < 4; e++) {
            f16x2 w2 = h2cast(Wv[e]);
            #pragma unroll
            for (int a = 0; a < 8; a++) {
                f16x2 av = h2cast(Aa[a][e]);
                #pragma unroll
                for (int c = 0; c < 4; c++) {
                    f16x2 pre = av + h2cast(Bb[c][e]);
                    f16x2 act = __builtin_elementwise_max(pre, zz);
                    acc[a][c] = __builtin_amdgcn_fdot2(act, w2, acc[a][c], false);
                }
            }
        }
    }

    #pragma unroll
    for (int a = 0; a < 8; a++) {
        int i = i0 + ty + 16 * a;
        #pragma unroll
        for (int c = 0; c < 4; c++) {
            float av = acc[a][c];
            float tt = av * 0.25f;
            float dd = fabsf(tt);
            float ss = sqrtf(fmaxf(0.5f - dd * dd, 0.f));
            float p0i = (ss + tt) * (ss + tt);
            float p0 = (dd >= 0.5f) ? (tt > 0.f ? 1.f : 0.f) : p0i;
            float val = fmaf(p0, w3d, w3b);
            int j = j0 + tx + 16 * c;
            if (i == j) val = 0.f;
            out[((size_t)bk * N_ + i) * N_ + j] = val;
        }
    }
}

// ---------------------------------------------------------------------------
extern "C" void kernel_launch(void* const* d_in, const int* in_sizes, int n_in,
                              void* d_out, int out_size, void* d_ws, size_t ws_size,
                              hipStream_t stream) {
    (void)in_sizes; (void)n_in; (void)out_size; (void)ws_size;
    const float* E  = (const float*)d_in[0];
    const float* W1 = (const float*)d_in[1];
    const float* b1 = (const float*)d_in[2];
    const float* W2 = (const float*)d_in[3];
    const float* b2 = (const float*)d_in[4];
    const float* W3 = (const float*)d_in[5];
    const float* b3 = (const float*)d_in[6];
    float* out = (float*)d_out;

    char* ws = (char*)d_ws;
    unsigned* wdh    = (unsigned*)ws;                    // K*64 half2 = 2 KB
    float*    consts = (float*)(ws + 4096);              // K*4 floats
    __half*   Eh     = (__half*)(ws + 8192);             // 512 KB
    __half*   Wh     = (__half*)(ws + 8192 + 524288);    // 512 KB

    prep_all<<<321, 256, 0, stream>>>(E, W1, W2, b2, W3, b3, Eh, Wh, wdh, consts);
    fused_kernel<<<B_ * K_ * 8, 256, 0, stream>>>(Eh, Wh, b1, wdh, consts, out);
}